// Round 6
// baseline (164.052 us; speedup 1.0000x reference)
//
#include <hip/hip_runtime.h>
#include <hip/hip_bf16.h>
#include <math.h>

#define NA 2048   // agents (2^11)
#define TT 20     // timesteps
#define KK 32     // neighbors
#define CC 32     // in channels
#define OO 64     // out channels / hidden
#define GG 256    // 4*OO gates
#define SW 88     // feat_sh row stride in shorts
#define GXP 264   // gx_sh row stride in shorts

typedef __attribute__((ext_vector_type(8))) short short8;
typedef __attribute__((ext_vector_type(4))) float float4v;
typedef __attribute__((ext_vector_type(4))) unsigned uint4v;

__device__ __forceinline__ float fast_rcp(float x) {
    return __builtin_amdgcn_rcpf(x);
}
__device__ __forceinline__ float sigm(float x) {
    return fast_rcp(1.f + __expf(-x));
}
__device__ __forceinline__ float tanh_fast(float x) {
    return 1.f - 2.f * fast_rcp(1.f + __expf(2.f * x));
}
// bf16 RNE on raw bits (ties-to-even; NaN not expected here). 3-4 VALU ops
// vs ~8 for the library __float2bfloat16.
__device__ __forceinline__ unsigned cvt_rne(float f) {
    unsigned u = __float_as_uint(f);
    return (u + 0x7FFFu + ((u >> 16) & 1u)) >> 16;
}
__device__ __forceinline__ unsigned pack2(float a, float b) {
    return cvt_rne(a) | (cvt_rne(b) << 16);
}
__device__ __forceinline__ float bf_lo(unsigned u) {
    return __uint_as_float(u << 16);
}
__device__ __forceinline__ float bf_hi(unsigned u) {
    return __uint_as_float(u & 0xffff0000u);
}

// P[t][n][o] = sum_c x[n][t][c] * conv_w[o][c], stored bf16 (128B rows).
// Block 0 additionally pre-converts w_ih/w_hh to bf16 and precomputes the
// folded gate bias (b_ih + b_hh + conv_b @ w_ih^T) so downstream kernels do
// zero weight conversion / bias arithmetic per wave.
__global__ __launch_bounds__(256) void proj_kernel(
    const float* __restrict__ x, const float* __restrict__ conv_w,
    const float* __restrict__ conv_b, const float* __restrict__ w_ih,
    const float* __restrict__ w_hh, const float* __restrict__ b_ih,
    const float* __restrict__ b_hh,
    __hip_bfloat16* __restrict__ P, unsigned short* __restrict__ wihb,
    unsigned short* __restrict__ whhb, float* __restrict__ biasT)
{
    const int tid = threadIdx.x;
    if (blockIdx.x == 0) {   // prep block
        for (int e = tid; e < 4 * OO * OO; e += 256) {
            wihb[e] = (unsigned short)cvt_rne(w_ih[e]);
            whhb[e] = (unsigned short)cvt_rne(w_hh[e]);
        }
        float bj = b_ih[tid] + b_hh[tid];
        #pragma unroll
        for (int o = 0; o < OO; o += 4) {
            float4 cb = *(const float4*)(conv_b + o);
            float4 wr = *(const float4*)(w_ih + (size_t)tid * OO + o);
            bj = fmaf(cb.x, wr.x, bj); bj = fmaf(cb.y, wr.y, bj);
            bj = fmaf(cb.z, wr.z, bj); bj = fmaf(cb.w, wr.w, bj);
        }
        biasT[tid] = bj;
        return;
    }
    const int lane = tid & 63;
    const int wv = tid >> 6;
    float w[CC];
    #pragma unroll
    for (int c = 0; c < CC; c += 4) {
        float4 v = *(const float4*)(conv_w + lane * CC + c);
        w[c] = v.x; w[c + 1] = v.y; w[c + 2] = v.z; w[c + 3] = v.w;
    }
    const int rbase = (blockIdx.x - 1) * 16 + wv * 4;
    #pragma unroll
    for (int i = 0; i < 4; ++i) {
        int r = rbase + i;                    // r = n*TT + t (x row order)
        const float* xr = x + (size_t)r * CC;
        float a0 = 0.f, a1 = 0.f;
        #pragma unroll
        for (int c = 0; c < CC; c += 8) {
            float4 v = *(const float4*)(xr + c);
            float4 u = *(const float4*)(xr + c + 4);
            a0 = fmaf(v.x, w[c], a0);     a0 = fmaf(v.y, w[c + 1], a0);
            a0 = fmaf(v.z, w[c + 2], a0); a0 = fmaf(v.w, w[c + 3], a0);
            a1 = fmaf(u.x, w[c + 4], a1); a1 = fmaf(u.y, w[c + 5], a1);
            a1 = fmaf(u.z, w[c + 6], a1); a1 = fmaf(u.w, w[c + 7], a1);
        }
        int n = r / TT;
        int t = r - n * TT;
        ((unsigned short*)P)[(((size_t)t << 11) + n) * OO + lane] =
            (unsigned short)cvt_rne(a0 + a1);
    }
}

// Gather-max + gate matmul (MFMA). R5 post-mortem: latency-bound at 12
// waves/CU (self-capped). Now 6 blocks/CU (24 waves) + per-wave overhead
// stripped: bf16 weights preloaded (zero cvt), bias precomputed, epilogue
// coalesced through LDS (2 dwordx4 stores vs 16 scattered 2B stores).
__global__ __launch_bounds__(256, 6) void gatemm_kernel(
    const __hip_bfloat16* __restrict__ P, const int* __restrict__ A,
    const unsigned short* __restrict__ wihb, const float* __restrict__ biasT,
    __hip_bfloat16* __restrict__ gx)
{
    const int tid = threadIdx.x;
    const int lane = tid & 63;
    const int wv = tid >> 6;
    const int l15 = lane & 15;
    const int q = lane >> 4;

    const int bs = (blockIdx.x & 7) * 320 + (blockIdx.x >> 3);  // XCD swizzle
    const int r0 = bs << 4;                  // first row, r = t*NA + n
    const int t = r0 >> 11;
    const int n0 = r0 & (NA - 1);
    const unsigned short* Pb = (const unsigned short*)P + ((size_t)t << 17);

    __shared__ __align__(16) unsigned short feat_sh[16 * SW];
    __shared__ __align__(16) unsigned short gx_sh[16 * GXP];

    // bias values for this thread's 4 output columns (early, to hide)
    float bv[4];
    #pragma unroll
    for (int tt2 = 0; tt2 < 4; ++tt2)
        bv[tt2] = biasT[wv * 64 + tt2 * 16 + l15];

    // B fragments straight from preconverted bf16 (8 dwordx4, zero cvt):
    // B[k][j] = w_ih[j][k]
    short8 bfrag[4][2];
    #pragma unroll
    for (int tt2 = 0; tt2 < 4; ++tt2) {
        int j = wv * 64 + tt2 * 16 + l15;
        #pragma unroll
        for (int ks = 0; ks < 2; ++ks)
            bfrag[tt2][ks] =
                *(const short8*)(wihb + ((size_t)j << 6) + ks * 32 + q * 8);
    }

    // ---- gather-max ----
    const int i_row = lane >> 4;        // 0..3: which of the wave's 4 rows
    const int ko2   = (lane >> 3) & 1;  // neighbor parity
    const int oc    = lane & 7;         // channel oct (8 bf16 = 16B)

    const int myrow = r0 + wv * 4 + i_row;
    const int* aRow = A + ((size_t)myrow << 5) + ko2;

    int ai[16];
    #pragma unroll
    for (int g = 0; g < 16; ++g) ai[g] = aRow[g * 2];   // k = 2g + ko2
    uint4v sv = *(const uint4v*)(Pb + ((size_t)(n0 + wv * 4 + i_row) << 6) + oc * 8);
    asm volatile("" ::: "memory");

    uint4v pv[16];
    #pragma unroll
    for (int g = 0; g < 16; ++g)
        pv[g] = *(const uint4v*)(Pb + ((size_t)ai[g] << 6) + oc * 8);
    asm volatile("" ::: "memory");

    float mx[8];
    #pragma unroll
    for (int e = 0; e < 8; ++e) mx[e] = -INFINITY;
    #pragma unroll
    for (int g = 0; g < 16; ++g) {
        uint4v v = pv[g];
        mx[0] = fmaxf(mx[0], bf_lo(v[0])); mx[1] = fmaxf(mx[1], bf_hi(v[0]));
        mx[2] = fmaxf(mx[2], bf_lo(v[1])); mx[3] = fmaxf(mx[3], bf_hi(v[1]));
        mx[4] = fmaxf(mx[4], bf_lo(v[2])); mx[5] = fmaxf(mx[5], bf_hi(v[2]));
        mx[6] = fmaxf(mx[6], bf_lo(v[3])); mx[7] = fmaxf(mx[7], bf_hi(v[3]));
    }
    #pragma unroll
    for (int e = 0; e < 8; ++e)
        mx[e] = fmaxf(mx[e], __shfl_xor(mx[e], 8, 64));  // combine parities

    if (ko2 == 0) {
        uint4v pk;
        pk[0] = pack2(mx[0] - bf_lo(sv[0]), mx[1] - bf_hi(sv[0]));
        pk[1] = pack2(mx[2] - bf_lo(sv[1]), mx[3] - bf_hi(sv[1]));
        pk[2] = pack2(mx[4] - bf_lo(sv[2]), mx[5] - bf_hi(sv[2]));
        pk[3] = pack2(mx[6] - bf_lo(sv[3]), mx[7] - bf_hi(sv[3]));
        *(uint4v*)&feat_sh[(wv * 4 + i_row) * SW + oc * 8] = pk;
    }
    __syncthreads();

    float4v acc[4] = {{0.f, 0.f, 0.f, 0.f}, {0.f, 0.f, 0.f, 0.f},
                      {0.f, 0.f, 0.f, 0.f}, {0.f, 0.f, 0.f, 0.f}};
    #pragma unroll
    for (int ks = 0; ks < 2; ++ks) {
        short8 af = *(const short8*)(&feat_sh[l15 * SW + ks * 32 + q * 8]);
        #pragma unroll
        for (int tt2 = 0; tt2 < 4; ++tt2)
            acc[tt2] = __builtin_amdgcn_mfma_f32_16x16x32_bf16(
                af, bfrag[tt2][ks], acc[tt2], 0, 0, 0);
    }

    // Epilogue: +bias, bf16, stage in LDS, store coalesced (tile is one
    // contiguous 8KB span of gx).
    #pragma unroll
    for (int tt2 = 0; tt2 < 4; ++tt2) {
        int j = wv * 64 + tt2 * 16 + l15;
        #pragma unroll
        for (int rg = 0; rg < 4; ++rg)
            gx_sh[(q * 4 + rg) * GXP + j] =
                (unsigned short)cvt_rne(acc[tt2][rg] + bv[tt2]);
    }
    __syncthreads();
    {
        const int m = tid >> 4;
        const int j0 = (tid & 15) * 16;
        uint4v d0 = *(const uint4v*)&gx_sh[m * GXP + j0];
        uint4v d1 = *(const uint4v*)&gx_sh[m * GXP + j0 + 8];
        unsigned short* gp_out = (unsigned short*)gx + ((size_t)(r0 + m) << 8) + j0;
        *(uint4v*)gp_out = d0;
        *(uint4v*)(gp_out + 8) = d1;
    }
}

// Serial recurrence via MFMA: 8 agents/block (256 blocks -> full GPU).
// Wave w computes gate-plane w: D[agent][ch] = h @ w_hh[w*64+ch][:]^T.
// A-frag rows 8..15 are kept exactly zero (junk rows never stored).
__global__ __launch_bounds__(256, 2) void lstm_kernel(
    const __hip_bfloat16* __restrict__ gx, const unsigned short* __restrict__ whhb,
    float* __restrict__ out)
{
    const int tid = threadIdx.x;
    const int lane = tid & 63;
    const int wv = tid >> 6;          // gate plane
    const int l15 = lane & 15;
    const int q = lane >> 4;
    const int a0 = blockIdx.x * 8;
    const int a = tid >> 4;           // pointwise: "agent row" 0..15
    const int c0 = (tid & 15) * 4;    // pointwise: first channel
    const int ag = (a < 8) ? (a0 + a) : (NA - 1);   // clamp junk rows

    // B-frags from preconverted bf16: B[k][ch] = w_hh[wv*64 + ch][k]
    short8 bfrag[4][2];
    #pragma unroll
    for (int tt2 = 0; tt2 < 4; ++tt2) {
        int row = wv * 64 + tt2 * 16 + l15;
        #pragma unroll
        for (int ks = 0; ks < 2; ++ks)
            bfrag[tt2][ks] =
                *(const short8*)(whhb + ((size_t)row << 6) + ks * 32 + q * 8);
    }

    __shared__ __align__(16) unsigned short h_sh[16 * 72];  // bf16, pad 72
    __shared__ float gp[4][16][68];                         // gate planes

    {   // h = 0 (all 16 rows; rows 8..15 stay zero forever)
        uint2 z; z.x = 0u; z.y = 0u;
        *(uint2*)&h_sh[a * 72 + c0] = z;
    }
    float cst[4] = {0.f, 0.f, 0.f, 0.f};

    const unsigned short* gxp = (const unsigned short*)gx;
    uint2 gxv[4];
    #pragma unroll
    for (int g = 0; g < 4; ++g)
        gxv[g] = *(const uint2*)(gxp + ((size_t)ag << 8) + g * 64 + c0);

    for (int t = 0; t < TT; ++t) {
        __syncthreads();  // h_sh ready (init or previous pointwise)

        float4v acc[4] = {{0.f, 0.f, 0.f, 0.f}, {0.f, 0.f, 0.f, 0.f},
                          {0.f, 0.f, 0.f, 0.f}, {0.f, 0.f, 0.f, 0.f}};
        #pragma unroll
        for (int ks = 0; ks < 2; ++ks) {
            short8 af = *(const short8*)(&h_sh[l15 * 72 + ks * 32 + q * 8]);
            #pragma unroll
            for (int tt2 = 0; tt2 < 4; ++tt2)
                acc[tt2] = __builtin_amdgcn_mfma_f32_16x16x32_bf16(
                    af, bfrag[tt2][ks], acc[tt2], 0, 0, 0);
        }
        #pragma unroll
        for (int tt2 = 0; tt2 < 4; ++tt2)
            #pragma unroll
            for (int rg = 0; rg < 4; ++rg)
                gp[wv][q * 4 + rg][tt2 * 16 + l15] = acc[tt2][rg];

        // prefetch next step's gx while gp settles
        uint2 gxn[4];
        int tn = (t + 1 < TT) ? t + 1 : t;
        #pragma unroll
        for (int g = 0; g < 4; ++g)
            gxn[g] = *(const uint2*)(gxp + (((size_t)tn << 11) + ag) * GG
                                     + g * 64 + c0);
        __syncthreads();  // gp ready

        float4 gv0 = *(const float4*)&gp[0][a][c0];
        float4 gv1 = *(const float4*)&gp[1][a][c0];
        float4 gv2 = *(const float4*)&gp[2][a][c0];
        float4 gv3 = *(const float4*)&gp[3][a][c0];
        float hv[4];
        {
            float gi[4] = {gv0.x + bf_lo(gxv[0].x), gv0.y + bf_hi(gxv[0].x),
                           gv0.z + bf_lo(gxv[0].y), gv0.w + bf_hi(gxv[0].y)};
            float gf[4] = {gv1.x + bf_lo(gxv[1].x), gv1.y + bf_hi(gxv[1].x),
                           gv1.z + bf_lo(gxv[1].y), gv1.w + bf_hi(gxv[1].y)};
            float gz[4] = {gv2.x + bf_lo(gxv[2].x), gv2.y + bf_hi(gxv[2].x),
                           gv2.z + bf_lo(gxv[2].y), gv2.w + bf_hi(gxv[2].y)};
            float go[4] = {gv3.x + bf_lo(gxv[3].x), gv3.y + bf_hi(gxv[3].x),
                           gv3.z + bf_lo(gxv[3].y), gv3.w + bf_hi(gxv[3].y)};
            #pragma unroll
            for (int e = 0; e < 4; ++e) {
                float ig = sigm(gi[e]);
                float fg = sigm(gf[e]);
                float zg = tanh_fast(gz[e]);
                float og = sigm(go[e]);
                cst[e] = fmaf(fg, cst[e], ig * zg);
                hv[e] = og * tanh_fast(cst[e]);
            }
        }
        {   // rows 8..15 must stay zero (they feed the MFMA A-frag)
            uint2 pk;
            if (a < 8) {
                pk.x = pack2(hv[0], hv[1]);
                pk.y = pack2(hv[2], hv[3]);
            } else { pk.x = 0u; pk.y = 0u; }
            *(uint2*)&h_sh[a * 72 + c0] = pk;
        }
        if (a < 8) {
            float4 ho; ho.x = hv[0]; ho.y = hv[1]; ho.z = hv[2]; ho.w = hv[3];
            *(float4*)(out + (((size_t)ag * TT + t) << 6) + c0) = ho;
            if (t == TT - 1) {
                size_t hb = (size_t)NA * TT * OO;
                *(float4*)(out + hb + ((size_t)ag << 6) + c0) = ho;
                float4 co; co.x = cst[0]; co.y = cst[1]; co.z = cst[2]; co.w = cst[3];
                *(float4*)(out + hb + ((size_t)NA << 6) + ((size_t)ag << 6) + c0) = co;
            }
        }
        gxv[0] = gxn[0]; gxv[1] = gxn[1]; gxv[2] = gxn[2]; gxv[3] = gxn[3];
    }
}

extern "C" void kernel_launch(void* const* d_in, const int* in_sizes, int n_in,
                              void* d_out, int out_size, void* d_ws, size_t ws_size,
                              hipStream_t stream) {
    const float* x      = (const float*)d_in[0];
    const int*   A      = (const int*)  d_in[1];
    const float* conv_w = (const float*)d_in[2];
    const float* conv_b = (const float*)d_in[3];
    const float* w_ih   = (const float*)d_in[4];
    const float* w_hh   = (const float*)d_in[5];
    const float* b_ih   = (const float*)d_in[6];
    const float* b_hh   = (const float*)d_in[7];
    float* out = (float*)d_out;

    char* ws = (char*)d_ws;
    __hip_bfloat16* P  = (__hip_bfloat16*)ws;                    // 5.25 MB
    size_t offGx = (size_t)TT * NA * OO * 2;
    __hip_bfloat16* gx = (__hip_bfloat16*)(ws + offGx);          // 21 MB
    size_t offW  = offGx + (size_t)TT * NA * GG * 2;
    unsigned short* wihb = (unsigned short*)(ws + offW);         // 32 KB
    unsigned short* whhb = wihb + 4 * OO * OO;                   // 32 KB
    float* biasT = (float*)(whhb + 4 * OO * OO);                 // 1 KB

    hipLaunchKernelGGL(proj_kernel, dim3(NA * TT / 16 + 1), dim3(256), 0, stream,
                       x, conv_w, conv_b, w_ih, w_hh, b_ih, b_hh,
                       P, wihb, whhb, biasT);
    hipLaunchKernelGGL(gatemm_kernel, dim3(NA * TT / 16), dim3(256), 0, stream,
                       P, A, wihb, biasT, gx);
    hipLaunchKernelGGL(lstm_kernel, dim3(NA / 8), dim3(256), 0, stream,
                       gx, whhb, out);
}